// Round 1
// baseline (482.232 us; speedup 1.0000x reference)
//
#include <hip/hip_runtime.h>
#include <hip/hip_bf16.h>

typedef __bf16 bf16_t;
typedef __bf16 bf16x8 __attribute__((ext_vector_type(8)));
typedef float f32x4 __attribute__((ext_vector_type(4)));

#define MFMA16(a, b, c) __builtin_amdgcn_mfma_f32_16x16x32_bf16((a), (b), (c), 0, 0, 0)

constexpr int BATCH = 8, CH = 256, IC = 128, NPOS = 4096;
// softmax scale: 1/(sqrt(128)*0.05) * log2(e)
constexpr float SM_C = 2.5503488f;

// ---- workspace layout (bytes) ----
// x_t bf16 [8][4096][256] ; reused later as y_t bf16 [8][4096][128]
constexpr size_t OFF_XT    = 0;
constexpr size_t OFF_QT    = 16777216;  // bf16 [8][4096][128] (centered)
constexpr size_t OFF_KT    = 25165824;  // bf16 [8][4096][128] (centered)
constexpr size_t OFF_V     = 33554432;  // bf16 [8][128][4096]
constexpr size_t OFF_WQKV  = 41943040;  // bf16 [384][256]
constexpr size_t OFF_WOUT  = 42139648;  // bf16 [256][128]
constexpr size_t OFF_XMEAN = 42205184;  // f32 [8][256]
constexpr size_t OFF_QKM   = 42213376;  // f32 [8][256]

// ---------------- small prep kernels ----------------
__global__ void k_convert_w(const float* __restrict__ wqkv, const float* __restrict__ wout,
                            bf16_t* __restrict__ wqkv_b, bf16_t* __restrict__ wout_b) {
    int idx = blockIdx.x * 256 + threadIdx.x;
    if (idx < 384 * 256) wqkv_b[idx] = (bf16_t)wqkv[idx];
    int j = idx - 384 * 256;
    if (j >= 0 && j < 256 * 128) wout_b[j] = (bf16_t)wout[j];
}

__global__ void k_xmean(const float* __restrict__ x, float* __restrict__ xmean) {
    int c = blockIdx.x, b = blockIdx.y;
    const float4* xv = (const float4*)(x + ((size_t)(b * CH + c)) * NPOS);
    float s = 0.f;
#pragma unroll
    for (int r = 0; r < 4; r++) {
        float4 v = xv[r * 256 + threadIdx.x];
        s += v.x + v.y + v.z + v.w;
    }
    __shared__ float red[256];
    red[threadIdx.x] = s;
    __syncthreads();
    for (int st = 128; st > 0; st >>= 1) {
        if (threadIdx.x < st) red[threadIdx.x] += red[threadIdx.x + st];
        __syncthreads();
    }
    if (threadIdx.x == 0) xmean[b * CH + c] = red[0] * (1.0f / NPOS);
}

// qkmean[b][o] = sum_c w_qkv[o][c] * xmean[b][c]   (no bias: it cancels in centering)
__global__ void k_qkmean(const float* __restrict__ wqkv, const float* __restrict__ xmean,
                         float* __restrict__ qkm) {
    int o = blockIdx.x, b = blockIdx.y, lane = threadIdx.x;
    float4 w = ((const float4*)(wqkv + (size_t)o * CH))[lane];
    float4 xm = ((const float4*)(xmean + b * CH))[lane];
    float s = w.x * xm.x + w.y * xm.y + w.z * xm.z + w.w * xm.w;
#pragma unroll
    for (int m = 1; m < 64; m <<= 1) s += __shfl_xor(s, m, 64);
    if (lane == 0) qkm[b * CH + o] = s;
}

// x [b][256][4096] f32 -> x_t [b][4096][256] bf16
__global__ void k_transpose(const float* __restrict__ x, bf16_t* __restrict__ xt) {
    __shared__ float t[32][33];
    int p0 = blockIdx.x * 32, c0 = blockIdx.y * 32, b = blockIdx.z;
    int i = threadIdx.x >> 5, j = threadIdx.x & 31;
#pragma unroll
    for (int q = 0; q < 4; q++) {
        int c = c0 + q * 8 + i;
        t[q * 8 + i][j] = x[((size_t)(b * CH + c)) * NPOS + p0 + j];
    }
    __syncthreads();
#pragma unroll
    for (int q = 0; q < 4; q++) {
        int p = p0 + q * 8 + i;
        xt[((size_t)(b * NPOS + p)) * CH + c0 + j] = (bf16_t)t[j][q * 8 + i];
    }
}

// ---------------- QKV projection ----------------
// grid 768: b = bid&7 (XCD pin), sec = q/k/v, 32 p-tiles of 128. block 256 (4 waves, 64x64 each).
__global__ __launch_bounds__(256, 2) void k_qkv(const bf16_t* __restrict__ xt,
                                                const bf16_t* __restrict__ wqkv_b,
                                                const float* __restrict__ qkm,
                                                const float* __restrict__ b_qkv,
                                                bf16_t* __restrict__ qt, bf16_t* __restrict__ kt,
                                                bf16_t* __restrict__ v) {
    int bid = blockIdx.x;
    int b = bid & 7;
    int r0 = bid >> 3;  // 0..95
    int sec = r0 % 3;
    int pt = r0 / 3;
    int p0 = pt * 128;
    int wid = threadIdx.x >> 6, lane = threadIdx.x & 63;
    int g = lane >> 4, li = lane & 15;
    int wr = wid >> 1, wc = wid & 1;
    f32x4 acc[4][4] = {};
    if (sec < 2) {
        // D[p][o]: A = x_t rows p (K=c contig), B = w rows o (K=c contig)
        int ob = sec * 128;
#pragma unroll 1
        for (int kk = 0; kk < 8; kk++) {
            bf16x8 af[4], bfg[4];
#pragma unroll
            for (int fa = 0; fa < 4; fa++) {
                int p = p0 + wr * 64 + fa * 16 + li;
                af[fa] = *(const bf16x8*)(xt + ((size_t)(b * NPOS + p)) * CH + kk * 32 + g * 8);
            }
#pragma unroll
            for (int fb = 0; fb < 4; fb++) {
                int o = ob + wc * 64 + fb * 16 + li;
                bfg[fb] = *(const bf16x8*)(wqkv_b + (size_t)o * CH + kk * 32 + g * 8);
            }
#pragma unroll
            for (int fa = 0; fa < 4; fa++)
#pragma unroll
                for (int fb = 0; fb < 4; fb++) acc[fa][fb] = MFMA16(af[fa], bfg[fb], acc[fa][fb]);
        }
        bf16_t* dst = (sec == 0) ? qt : kt;
#pragma unroll
        for (int fb = 0; fb < 4; fb++) {
            int ol = wc * 64 + fb * 16 + li;
            float mean = qkm[b * CH + sec * 128 + ol];
#pragma unroll
            for (int fa = 0; fa < 4; fa++)
#pragma unroll
                for (int r = 0; r < 4; r++) {
                    int p = p0 + wr * 64 + fa * 16 + g * 4 + r;
                    dst[((size_t)(b * NPOS + p)) * IC + ol] = (bf16_t)(acc[fa][fb][r] - mean);
                }
        }
    } else {
        // v: D[o][p]: A = w rows 256+o, B = x_t rows p
#pragma unroll 1
        for (int kk = 0; kk < 8; kk++) {
            bf16x8 af[4], bfg[4];
#pragma unroll
            for (int fa = 0; fa < 4; fa++) {
                int o = 256 + wr * 64 + fa * 16 + li;
                af[fa] = *(const bf16x8*)(wqkv_b + (size_t)o * CH + kk * 32 + g * 8);
            }
#pragma unroll
            for (int fb = 0; fb < 4; fb++) {
                int p = p0 + wc * 64 + fb * 16 + li;
                bfg[fb] = *(const bf16x8*)(xt + ((size_t)(b * NPOS + p)) * CH + kk * 32 + g * 8);
            }
#pragma unroll
            for (int fa = 0; fa < 4; fa++)
#pragma unroll
                for (int fb = 0; fb < 4; fb++) acc[fa][fb] = MFMA16(af[fa], bfg[fb], acc[fa][fb]);
        }
#pragma unroll
        for (int fa = 0; fa < 4; fa++)
#pragma unroll
            for (int r = 0; r < 4; r++) {
                int oe = wr * 64 + fa * 16 + g * 4 + r;  // 0..127
                float bias = b_qkv[256 + oe];
#pragma unroll
                for (int fb = 0; fb < 4; fb++) {
                    int p = p0 + wc * 64 + fb * 16 + li;
                    v[((size_t)(b * IC + oe)) * NPOS + p] = (bf16_t)(acc[fa][fb][r] + bias);
                }
            }
    }
}

// ---------------- flash attention ----------------
// rows i <- k_t ("queries"), cols j <- q_t ("keys"), values v[c][j].
// grid 256 (b = bid&7, 32 i-tiles of 128), 4 waves, each wave 32 i-rows.
__global__ __launch_bounds__(256, 1) void k_attn(const bf16_t* __restrict__ qt,
                                                 const bf16_t* __restrict__ kt,
                                                 const bf16_t* __restrict__ v,
                                                 bf16_t* __restrict__ yt) {
    __shared__ __attribute__((aligned(16))) bf16_t plds[4][32][72];
    int bid = blockIdx.x;
    int b = bid & 7;
    int it = bid >> 3;  // 0..31
    int wid = threadIdx.x >> 6, lane = threadIdx.x & 63;
    int g = lane >> 4, li = lane & 15;
    int iw0 = it * 128 + wid * 32;
    const bf16_t* ktb = kt + (size_t)b * NPOS * IC;
    const bf16_t* qtb = qt + (size_t)b * NPOS * IC;
    const bf16_t* vb = v + (size_t)b * IC * NPOS;

    bf16x8 a[2][4];
#pragma unroll
    for (int fi = 0; fi < 2; fi++)
#pragma unroll
        for (int kk = 0; kk < 4; kk++)
            a[fi][kk] = *(const bf16x8*)(ktb + (size_t)(iw0 + fi * 16 + li) * IC + kk * 32 + g * 8);

    f32x4 acc[2][8] = {};
    float m[2][4], l[2][4];
#pragma unroll
    for (int fi = 0; fi < 2; fi++)
#pragma unroll
        for (int r = 0; r < 4; r++) {
            m[fi][r] = -1e30f;
            l[fi][r] = 0.f;
        }

#pragma unroll 1
    for (int j0 = 0; j0 < NPOS; j0 += 64) {
        f32x4 s[2][4] = {};
#pragma unroll
        for (int jf = 0; jf < 4; jf++) {
            bf16x8 bq[4];
#pragma unroll
            for (int kk = 0; kk < 4; kk++)
                bq[kk] = *(const bf16x8*)(qtb + (size_t)(j0 + jf * 16 + li) * IC + kk * 32 + g * 8);
#pragma unroll
            for (int fi = 0; fi < 2; fi++)
#pragma unroll
                for (int kk = 0; kk < 4; kk++) s[fi][jf] = MFMA16(a[fi][kk], bq[kk], s[fi][jf]);
        }
        // online softmax (rows = g*4+r within each 16-frag; reduce over cols = li)
#pragma unroll
        for (int fi = 0; fi < 2; fi++) {
#pragma unroll
            for (int r = 0; r < 4; r++) {
                float mt = fmaxf(fmaxf(s[fi][0][r], s[fi][1][r]), fmaxf(s[fi][2][r], s[fi][3][r]));
#pragma unroll
                for (int msk = 1; msk < 16; msk <<= 1) mt = fmaxf(mt, __shfl_xor(mt, msk, 64));
                float mn = fmaxf(m[fi][r], mt);
                float alpha = exp2f((m[fi][r] - mn) * SM_C);
                m[fi][r] = mn;
                float ps = 0.f;
#pragma unroll
                for (int jf = 0; jf < 4; jf++) {
                    float p = exp2f((s[fi][jf][r] - mn) * SM_C);
                    s[fi][jf][r] = p;
                    ps += p;
                }
#pragma unroll
                for (int msk = 1; msk < 16; msk <<= 1) ps += __shfl_xor(ps, msk, 64);
                l[fi][r] = l[fi][r] * alpha + ps;
#pragma unroll
                for (int cf = 0; cf < 8; cf++) acc[fi][cf][r] *= alpha;
            }
        }
        // P -> LDS (per-wave buffer, row stride 72 bf16 breaks bank alignment)
#pragma unroll
        for (int fi = 0; fi < 2; fi++)
#pragma unroll
            for (int jf = 0; jf < 4; jf++)
#pragma unroll
                for (int r = 0; r < 4; r++)
                    plds[wid][fi * 16 + g * 4 + r][jf * 16 + li] = (bf16_t)s[fi][jf][r];
        // PV: A = P[i][j] from LDS, B = v[c][j] direct
#pragma unroll
        for (int jj = 0; jj < 2; jj++) {
            bf16x8 pf[2];
#pragma unroll
            for (int fi = 0; fi < 2; fi++)
                pf[fi] = *(const bf16x8*)(&plds[wid][fi * 16 + li][jj * 32 + g * 8]);
#pragma unroll
            for (int cf = 0; cf < 8; cf++) {
                bf16x8 vf =
                    *(const bf16x8*)(vb + (size_t)(cf * 16 + li) * NPOS + j0 + jj * 32 + g * 8);
#pragma unroll
                for (int fi = 0; fi < 2; fi++) acc[fi][cf] = MFMA16(pf[fi], vf, acc[fi][cf]);
            }
        }
    }
#pragma unroll
    for (int fi = 0; fi < 2; fi++)
#pragma unroll
        for (int r = 0; r < 4; r++) {
            float inv = 1.0f / l[fi][r];
            int i = iw0 + fi * 16 + g * 4 + r;
#pragma unroll
            for (int cf = 0; cf < 8; cf++)
                yt[((size_t)b * NPOS + i) * IC + cf * 16 + li] = (bf16_t)(acc[fi][cf][r] * inv);
        }
}

// ---------------- output projection + residual ----------------
// grid 512: b = bid&7, 2 oc-tiles x 32 p-tiles. D[oc][p], A = w_out rows, B = y_t rows.
__global__ __launch_bounds__(256, 2) void k_out(const bf16_t* __restrict__ yt,
                                                const bf16_t* __restrict__ wout_b,
                                                const float* __restrict__ x,
                                                const float* __restrict__ b_out,
                                                float* __restrict__ out) {
    int bid = blockIdx.x;
    int b = bid & 7;
    int r0 = bid >> 3;  // 0..63
    int oct = r0 & 1, pt = r0 >> 1;
    int p0 = pt * 128, oc0 = oct * 128;
    int wid = threadIdx.x >> 6, lane = threadIdx.x & 63;
    int g = lane >> 4, li = lane & 15;
    int wr = wid >> 1, wc = wid & 1;
    f32x4 acc[4][4] = {};
#pragma unroll
    for (int kk = 0; kk < 4; kk++) {
        bf16x8 af[4], bfg[4];
#pragma unroll
        for (int fa = 0; fa < 4; fa++) {
            int oc = oc0 + wr * 64 + fa * 16 + li;
            af[fa] = *(const bf16x8*)(wout_b + (size_t)oc * IC + kk * 32 + g * 8);
        }
#pragma unroll
        for (int fb = 0; fb < 4; fb++) {
            int p = p0 + wc * 64 + fb * 16 + li;
            bfg[fb] = *(const bf16x8*)(yt + ((size_t)(b * NPOS + p)) * IC + kk * 32 + g * 8);
        }
#pragma unroll
        for (int fa = 0; fa < 4; fa++)
#pragma unroll
            for (int fb = 0; fb < 4; fb++) acc[fa][fb] = MFMA16(af[fa], bfg[fb], acc[fa][fb]);
    }
#pragma unroll
    for (int fa = 0; fa < 4; fa++)
#pragma unroll
        for (int r = 0; r < 4; r++) {
            int oc = oc0 + wr * 64 + fa * 16 + g * 4 + r;
            float bias = b_out[oc];
#pragma unroll
            for (int fb = 0; fb < 4; fb++) {
                int p = p0 + wc * 64 + fb * 16 + li;
                size_t idx = ((size_t)(b * CH + oc)) * NPOS + p;
                out[idx] = acc[fa][fb][r] + x[idx] + bias;
            }
        }
}

extern "C" void kernel_launch(void* const* d_in, const int* in_sizes, int n_in, void* d_out,
                              int out_size, void* d_ws, size_t ws_size, hipStream_t stream) {
    const float* x = (const float*)d_in[0];
    const float* w_qkv = (const float*)d_in[1];
    const float* b_qkv = (const float*)d_in[2];
    const float* w_out = (const float*)d_in[3];
    const float* b_out = (const float*)d_in[4];
    float* out = (float*)d_out;
    char* ws = (char*)d_ws;

    bf16_t* xt = (bf16_t*)(ws + OFF_XT);
    bf16_t* yt = (bf16_t*)(ws + OFF_XT);  // reuses x_t region (x_t dead after k_qkv)
    bf16_t* qt = (bf16_t*)(ws + OFF_QT);
    bf16_t* kt = (bf16_t*)(ws + OFF_KT);
    bf16_t* v = (bf16_t*)(ws + OFF_V);
    bf16_t* wqkv_b = (bf16_t*)(ws + OFF_WQKV);
    bf16_t* wout_b = (bf16_t*)(ws + OFF_WOUT);
    float* xmean = (float*)(ws + OFF_XMEAN);
    float* qkm = (float*)(ws + OFF_QKM);

    k_convert_w<<<512, 256, 0, stream>>>(w_qkv, w_out, wqkv_b, wout_b);
    k_xmean<<<dim3(256, 8), 256, 0, stream>>>(x, xmean);
    k_qkmean<<<dim3(256, 8), 64, 0, stream>>>(w_qkv, xmean, qkm);
    k_transpose<<<dim3(128, 8, 8), 256, 0, stream>>>(x, xt);
    k_qkv<<<768, 256, 0, stream>>>(xt, wqkv_b, qkm, b_qkv, qt, kt, v);
    k_attn<<<256, 256, 0, stream>>>(qt, kt, v, yt);
    k_out<<<512, 256, 0, stream>>>(yt, wout_b, x, b_out, out);
}

// Round 2
// 194.700 us; speedup vs baseline: 2.4768x; 2.4768x over previous
//
#include <hip/hip_runtime.h>
#include <hip/hip_bf16.h>

typedef __bf16 bf16_t;
typedef __bf16 bf16x8 __attribute__((ext_vector_type(8)));
typedef float f32x4 __attribute__((ext_vector_type(4)));

#define MFMA16(a, b, c) __builtin_amdgcn_mfma_f32_16x16x32_bf16((a), (b), (c), 0, 0, 0)

constexpr int BATCH = 8, CH = 256, IC = 128, NPOS = 4096;
// softmax scale: 1/(sqrt(128)*0.05) * log2(e)
constexpr float SM_C = 2.5503488f;

// ---- workspace layout (bytes) ----
constexpr size_t OFF_XT    = 0;         // bf16 [8][4096][256]; reused as y_t bf16 [8][4096][128]
constexpr size_t OFF_QT    = 16777216;  // bf16 [8][4096][128] (centered)
constexpr size_t OFF_KT    = 25165824;  // bf16 [8][4096][128] (centered)
constexpr size_t OFF_V     = 33554432;  // bf16 [8][128][4096]
constexpr size_t OFF_WQKV  = 41943040;  // bf16 [384][256]
constexpr size_t OFF_WOUT  = 42139648;  // bf16 [256][128]
constexpr size_t OFF_XMEAN = 42205184;  // f32 [8][256]
constexpr size_t OFF_QKM   = 42213376;  // f32 [8][256]

__device__ __forceinline__ void gload_lds16(const char* g, char* lds) {
    __builtin_amdgcn_global_load_lds((const __attribute__((address_space(1))) unsigned int*)g,
                                     (__attribute__((address_space(3))) unsigned int*)lds, 16, 0,
                                     0);
}

// ---------------- small prep kernels ----------------
__global__ void k_convert_w(const float* __restrict__ wqkv, const float* __restrict__ wout,
                            bf16_t* __restrict__ wqkv_b, bf16_t* __restrict__ wout_b) {
    int idx = blockIdx.x * 256 + threadIdx.x;
    if (idx < 384 * 256) wqkv_b[idx] = (bf16_t)wqkv[idx];
    int j = idx - 384 * 256;
    if (j >= 0 && j < 256 * 128) wout_b[j] = (bf16_t)wout[j];
}

__global__ void k_xmean(const float* __restrict__ x, float* __restrict__ xmean) {
    int c = blockIdx.x, b = blockIdx.y;
    const float4* xv = (const float4*)(x + ((size_t)(b * CH + c)) * NPOS);
    float s = 0.f;
#pragma unroll
    for (int r = 0; r < 4; r++) {
        float4 v = xv[r * 256 + threadIdx.x];
        s += v.x + v.y + v.z + v.w;
    }
    __shared__ float red[256];
    red[threadIdx.x] = s;
    __syncthreads();
    for (int st = 128; st > 0; st >>= 1) {
        if (threadIdx.x < st) red[threadIdx.x] += red[threadIdx.x + st];
        __syncthreads();
    }
    if (threadIdx.x == 0) xmean[b * CH + c] = red[0] * (1.0f / NPOS);
}

// qkmean[b][o] = sum_c w_qkv[o][c] * xmean[b][c]   (no bias: it cancels in centering)
__global__ void k_qkmean(const float* __restrict__ wqkv, const float* __restrict__ xmean,
                         float* __restrict__ qkm) {
    int o = blockIdx.x, b = blockIdx.y, lane = threadIdx.x;
    float4 w = ((const float4*)(wqkv + (size_t)o * CH))[lane];
    float4 xm = ((const float4*)(xmean + b * CH))[lane];
    float s = w.x * xm.x + w.y * xm.y + w.z * xm.z + w.w * xm.w;
#pragma unroll
    for (int m = 1; m < 64; m <<= 1) s += __shfl_xor(s, m, 64);
    if (lane == 0) qkm[b * CH + o] = s;
}

// x [b][256][4096] f32 -> x_t [b][4096][256] bf16
__global__ void k_transpose(const float* __restrict__ x, bf16_t* __restrict__ xt) {
    __shared__ float t[32][33];
    int p0 = blockIdx.x * 32, c0 = blockIdx.y * 32, b = blockIdx.z;
    int i = threadIdx.x >> 5, j = threadIdx.x & 31;
#pragma unroll
    for (int q = 0; q < 4; q++) {
        int c = c0 + q * 8 + i;
        t[q * 8 + i][j] = x[((size_t)(b * CH + c)) * NPOS + p0 + j];
    }
    __syncthreads();
#pragma unroll
    for (int q = 0; q < 4; q++) {
        int p = p0 + q * 8 + i;
        xt[((size_t)(b * NPOS + p)) * CH + c0 + j] = (bf16_t)t[j][q * 8 + i];
    }
}

// ---------------- QKV projection ----------------
__global__ __launch_bounds__(256, 2) void k_qkv(const bf16_t* __restrict__ xt,
                                                const bf16_t* __restrict__ wqkv_b,
                                                const float* __restrict__ qkm,
                                                const float* __restrict__ b_qkv,
                                                bf16_t* __restrict__ qt, bf16_t* __restrict__ kt,
                                                bf16_t* __restrict__ v) {
    int bid = blockIdx.x;
    int b = bid & 7;
    int r0 = bid >> 3;  // 0..95
    int sec = r0 % 3;
    int pt = r0 / 3;
    int p0 = pt * 128;
    int wid = threadIdx.x >> 6, lane = threadIdx.x & 63;
    int g = lane >> 4, li = lane & 15;
    int wr = wid >> 1, wc = wid & 1;
    f32x4 acc[4][4] = {};
    if (sec < 2) {
        int ob = sec * 128;
#pragma unroll 1
        for (int kk = 0; kk < 8; kk++) {
            bf16x8 af[4], bfg[4];
#pragma unroll
            for (int fa = 0; fa < 4; fa++) {
                int p = p0 + wr * 64 + fa * 16 + li;
                af[fa] = *(const bf16x8*)(xt + ((size_t)(b * NPOS + p)) * CH + kk * 32 + g * 8);
            }
#pragma unroll
            for (int fb = 0; fb < 4; fb++) {
                int o = ob + wc * 64 + fb * 16 + li;
                bfg[fb] = *(const bf16x8*)(wqkv_b + (size_t)o * CH + kk * 32 + g * 8);
            }
#pragma unroll
            for (int fa = 0; fa < 4; fa++)
#pragma unroll
                for (int fb = 0; fb < 4; fb++) acc[fa][fb] = MFMA16(af[fa], bfg[fb], acc[fa][fb]);
        }
        bf16_t* dst = (sec == 0) ? qt : kt;
#pragma unroll
        for (int fb = 0; fb < 4; fb++) {
            int ol = wc * 64 + fb * 16 + li;
            float mean = qkm[b * CH + sec * 128 + ol];
#pragma unroll
            for (int fa = 0; fa < 4; fa++)
#pragma unroll
                for (int r = 0; r < 4; r++) {
                    int p = p0 + wr * 64 + fa * 16 + g * 4 + r;
                    dst[((size_t)(b * NPOS + p)) * IC + ol] = (bf16_t)(acc[fa][fb][r] - mean);
                }
        }
    } else {
#pragma unroll 1
        for (int kk = 0; kk < 8; kk++) {
            bf16x8 af[4], bfg[4];
#pragma unroll
            for (int fa = 0; fa < 4; fa++) {
                int o = 256 + wr * 64 + fa * 16 + li;
                af[fa] = *(const bf16x8*)(wqkv_b + (size_t)o * CH + kk * 32 + g * 8);
            }
#pragma unroll
            for (int fb = 0; fb < 4; fb++) {
                int p = p0 + wc * 64 + fb * 16 + li;
                bfg[fb] = *(const bf16x8*)(xt + ((size_t)(b * NPOS + p)) * CH + kk * 32 + g * 8);
            }
#pragma unroll
            for (int fa = 0; fa < 4; fa++)
#pragma unroll
                for (int fb = 0; fb < 4; fb++) acc[fa][fb] = MFMA16(af[fa], bfg[fb], acc[fa][fb]);
        }
#pragma unroll
        for (int fa = 0; fa < 4; fa++)
#pragma unroll
            for (int r = 0; r < 4; r++) {
                int oe = wr * 64 + fa * 16 + g * 4 + r;
                float bias = b_qkv[256 + oe];
#pragma unroll
                for (int fb = 0; fb < 4; fb++) {
                    int p = p0 + wc * 64 + fb * 16 + li;
                    v[((size_t)(b * IC + oe)) * NPOS + p] = (bf16_t)(acc[fa][fb][r] + bias);
                }
            }
    }
}

// ---------------- flash attention ----------------
// rows i <- k_t ("queries"), cols j <- q_t ("keys"), values v[c][j].
// grid 256 (b = bid&7, 32 i-tiles of 128). 4 waves x 32 rows.
// Per 64-j tile: q-tile [64][128] + v-tile [128][64] staged in LDS (XOR-swizzled,
// double-buffered, counted vmcnt). One-pass softmax (no max), l via ones-MFMA.
constexpr int TJ = 64;

__global__ __launch_bounds__(256, 1) void k_attn(const bf16_t* __restrict__ qt,
                                                 const bf16_t* __restrict__ kt,
                                                 const bf16_t* __restrict__ v,
                                                 bf16_t* __restrict__ yt) {
    // LDS: 2 x (q 16KB + v 16KB) dbuf, then per-wave P buffers [4][32][72] bf16
    __shared__ __attribute__((aligned(128))) char smem[2 * 32768 + 4 * 32 * 72 * 2];
    const int bid = blockIdx.x;
    const int b = bid & 7;
    const int it = bid >> 3;  // 0..31
    const int wid = threadIdx.x >> 6, lane = threadIdx.x & 63;
    const int g = lane >> 4, li = lane & 15;
    const int iw0 = it * 128 + wid * 32;
    const bf16_t* ktb = kt + (size_t)b * NPOS * IC;
    const bf16_t* qtb = qt + (size_t)b * NPOS * IC;
    const bf16_t* vb = v + (size_t)b * IC * NPOS;
    bf16_t* plds = (bf16_t*)(smem + 65536) + wid * 32 * 72;

    // staging lane offsets (pre-swizzled global source: chunk ^= row&7)
    int qoff_[4], voff_[4];
#pragma unroll
    for (int u = 0; u < 4; u++) {
        int t = wid * 4 + u;
        int qrow = 4 * t + (lane >> 4);  // q-tile: 4 rows x 16 chunks per 1KB inst
        qoff_[u] = qrow * 256 + (((lane & 15) ^ (qrow & 7)) << 4);
        int vrow = 8 * t + (lane >> 3);  // v-tile: 8 rows x 8 chunks per 1KB inst
        voff_[u] = vrow * 8192 + (((lane & 7) ^ (vrow & 7)) << 4);
    }

    auto stage = [&](int dstpar, int sj) {
        const char* qs = (const char*)qtb + (size_t)sj * 256;
        const char* vs = (const char*)vb + (size_t)sj * 2;
        char* qd = smem + dstpar * 32768;
        char* vd = qd + 16384;
#pragma unroll
        for (int u = 0; u < 4; u++) {
            gload_lds16(qs + qoff_[u], qd + (wid * 4 + u) * 1024);
            gload_lds16(vs + voff_[u], vd + (wid * 4 + u) * 1024);
        }
    };

    stage(0, 0);  // prologue: fill buf0 (8 loads in flight)

    // A-fragments: this wave's 32 k-rows, held in registers for the whole kernel
    bf16x8 a[2][4];
#pragma unroll
    for (int fi = 0; fi < 2; fi++)
#pragma unroll
        for (int kk = 0; kk < 4; kk++)
            a[fi][kk] = *(const bf16x8*)(ktb + (size_t)(iw0 + fi * 16 + li) * IC + kk * 32 + g * 8);

    bf16_t one_ = (bf16_t)1.0f;
    bf16x8 vones = {one_, one_, one_, one_, one_, one_, one_};

    f32x4 acc[2][8] = {};
    f32x4 accl[2] = {};

    auto body = [&](int par, int j0) {
        stage(par ^ 1, (j0 + TJ) & (NPOS - 1));  // prefetch next tile (8 loads)
        asm volatile("s_waitcnt vmcnt(8)" ::: "memory");  // cur tile's loads done
        __builtin_amdgcn_s_barrier();                     // all waves' quarters done
        asm volatile("" ::: "memory");
        const char* qb = smem + par * 32768;
        const char* vbuf = qb + 16384;
        // QK^T
        f32x4 s[2][4] = {};
#pragma unroll
        for (int jf = 0; jf < 4; jf++) {
            bf16x8 bq[4];
#pragma unroll
            for (int kk = 0; kk < 4; kk++)
                bq[kk] = *(const bf16x8*)(qb + (jf * 16 + li) * 256 +
                                          (((kk * 4 + g) ^ (li & 7)) << 4));
#pragma unroll
            for (int fi = 0; fi < 2; fi++)
#pragma unroll
                for (int kk = 0; kk < 4; kk++) s[fi][jf] = MFMA16(a[fi][kk], bq[kk], s[fi][jf]);
        }
        // one-pass softmax: P = exp2(S*C), straight to LDS (per-wave buffer)
#pragma unroll
        for (int fi = 0; fi < 2; fi++)
#pragma unroll
            for (int jf = 0; jf < 4; jf++)
#pragma unroll
                for (int r = 0; r < 4; r++)
                    plds[(fi * 16 + g * 4 + r) * 72 + jf * 16 + li] =
                        (bf16_t)exp2f(s[fi][jf][r] * SM_C);
        // PV (+ row-sum via ones-MFMA)
#pragma unroll
        for (int jj = 0; jj < 2; jj++) {
            bf16x8 pf[2];
#pragma unroll
            for (int fi = 0; fi < 2; fi++)
                pf[fi] = *(const bf16x8*)((const char*)plds +
                                          ((fi * 16 + li) * 72 + jj * 32 + g * 8) * 2);
#pragma unroll
            for (int fi = 0; fi < 2; fi++) accl[fi] = MFMA16(pf[fi], vones, accl[fi]);
#pragma unroll
            for (int cf = 0; cf < 8; cf++) {
                bf16x8 vf = *(const bf16x8*)(vbuf + (cf * 16 + li) * 128 +
                                             (((jj * 4 + g) ^ (li & 7)) << 4));
#pragma unroll
                for (int fi = 0; fi < 2; fi++) acc[fi][cf] = MFMA16(pf[fi], vf, acc[fi][cf]);
            }
        }
        asm volatile("" ::: "memory");
        __builtin_amdgcn_s_barrier();  // all reads of cur done before it's restaged
    };

#pragma unroll 1
    for (int j0 = 0; j0 < NPOS; j0 += 2 * TJ) {
        body(0, j0);
        body(1, j0 + TJ);
    }

#pragma unroll
    for (int fi = 0; fi < 2; fi++)
#pragma unroll
        for (int r = 0; r < 4; r++) {
            float inv = 1.0f / accl[fi][r];
            int i = iw0 + fi * 16 + g * 4 + r;
#pragma unroll
            for (int cf = 0; cf < 8; cf++)
                yt[((size_t)b * NPOS + i) * IC + cf * 16 + li] = (bf16_t)(acc[fi][cf][r] * inv);
        }
}

// ---------------- output projection + residual ----------------
__global__ __launch_bounds__(256, 2) void k_out(const bf16_t* __restrict__ yt,
                                                const bf16_t* __restrict__ wout_b,
                                                const float* __restrict__ x,
                                                const float* __restrict__ b_out,
                                                float* __restrict__ out) {
    int bid = blockIdx.x;
    int b = bid & 7;
    int r0 = bid >> 3;
    int oct = r0 & 1, pt = r0 >> 1;
    int p0 = pt * 128, oc0 = oct * 128;
    int wid = threadIdx.x >> 6, lane = threadIdx.x & 63;
    int g = lane >> 4, li = lane & 15;
    int wr = wid >> 1, wc = wid & 1;
    f32x4 acc[4][4] = {};
#pragma unroll
    for (int kk = 0; kk < 4; kk++) {
        bf16x8 af[4], bfg[4];
#pragma unroll
        for (int fa = 0; fa < 4; fa++) {
            int oc = oc0 + wr * 64 + fa * 16 + li;
            af[fa] = *(const bf16x8*)(wout_b + (size_t)oc * IC + kk * 32 + g * 8);
        }
#pragma unroll
        for (int fb = 0; fb < 4; fb++) {
            int p = p0 + wc * 64 + fb * 16 + li;
            bfg[fb] = *(const bf16x8*)(yt + ((size_t)(b * NPOS + p)) * IC + kk * 32 + g * 8);
        }
#pragma unroll
        for (int fa = 0; fa < 4; fa++)
#pragma unroll
            for (int fb = 0; fb < 4; fb++) acc[fa][fb] = MFMA16(af[fa], bfg[fb], acc[fa][fb]);
    }
#pragma unroll
    for (int fa = 0; fa < 4; fa++)
#pragma unroll
        for (int r = 0; r < 4; r++) {
            int oc = oc0 + wr * 64 + fa * 16 + g * 4 + r;
            float bias = b_out[oc];
#pragma unroll
            for (int fb = 0; fb < 4; fb++) {
                int p = p0 + wc * 64 + fb * 16 + li;
                size_t idx = ((size_t)(b * CH + oc)) * NPOS + p;
                out[idx] = acc[fa][fb][r] + x[idx] + bias;
            }
        }
}

extern "C" void kernel_launch(void* const* d_in, const int* in_sizes, int n_in, void* d_out,
                              int out_size, void* d_ws, size_t ws_size, hipStream_t stream) {
    const float* x = (const float*)d_in[0];
    const float* w_qkv = (const float*)d_in[1];
    const float* b_qkv = (const float*)d_in[2];
    const float* w_out = (const float*)d_in[3];
    const float* b_out = (const float*)d_in[4];
    float* out = (float*)d_out;
    char* ws = (char*)d_ws;

    bf16_t* xt = (bf16_t*)(ws + OFF_XT);
    bf16_t* yt = (bf16_t*)(ws + OFF_XT);  // reuses x_t region (x_t dead after k_qkv)
    bf16_t* qt = (bf16_t*)(ws + OFF_QT);
    bf16_t* kt = (bf16_t*)(ws + OFF_KT);
    bf16_t* v = (bf16_t*)(ws + OFF_V);
    bf16_t* wqkv_b = (bf16_t*)(ws + OFF_WQKV);
    bf16_t* wout_b = (bf16_t*)(ws + OFF_WOUT);
    float* xmean = (float*)(ws + OFF_XMEAN);
    float* qkm = (float*)(ws + OFF_QKM);

    k_convert_w<<<512, 256, 0, stream>>>(w_qkv, w_out, wqkv_b, wout_b);
    k_xmean<<<dim3(256, 8), 256, 0, stream>>>(x, xmean);
    k_qkmean<<<dim3(256, 8), 64, 0, stream>>>(w_qkv, xmean, qkm);
    k_transpose<<<dim3(128, 8, 8), 256, 0, stream>>>(x, xt);
    k_qkv<<<768, 256, 0, stream>>>(xt, wqkv_b, qkm, b_qkv, qt, kt, v);
    k_attn<<<256, 256, 0, stream>>>(qt, kt, v, yt);
    k_out<<<512, 256, 0, stream>>>(yt, wout_b, x, b_out, out);
}

// Round 3
// 163.315 us; speedup vs baseline: 2.9528x; 1.1922x over previous
//
#include <hip/hip_runtime.h>
#include <hip/hip_bf16.h>

typedef __bf16 bf16_t;
typedef __bf16 bf16x4 __attribute__((ext_vector_type(4)));
typedef __bf16 bf16x8 __attribute__((ext_vector_type(8)));
typedef float f32x4 __attribute__((ext_vector_type(4)));

#define MFMA16(a, b, c) __builtin_amdgcn_mfma_f32_16x16x32_bf16((a), (b), (c), 0, 0, 0)

constexpr int BATCH = 8, CH = 256, IC = 128, NPOS = 4096;
// softmax scale: 1/(sqrt(128)*0.05) * log2(e)
constexpr float SM_C = 2.5503488f;

// ---- workspace layout (bytes) ----
constexpr size_t OFF_XT    = 0;         // bf16 [8][4096][256] x_t; later pacc bf16 [8][2][4096][128] (exact fit)
constexpr size_t OFF_QT    = 16777216;  // bf16 [8][4096][128] (centered)
constexpr size_t OFF_KT    = 25165824;  // bf16 [8][4096][128] (centered); later yt bf16 [8][4096][128]
constexpr size_t OFF_V     = 33554432;  // bf16 [8][128][4096]
constexpr size_t OFF_WQKV  = 41943040;  // bf16 [384][256]
constexpr size_t OFF_WOUT  = 42139648;  // bf16 [256][128]
constexpr size_t OFF_XMEAN = 42205184;  // f32 [8][256]
constexpr size_t OFF_QKM   = 42213376;  // f32 [8][256]
constexpr size_t OFF_PL    = 42221568;  // f32 [8][2][4096]

__device__ __forceinline__ void gload_lds16(const char* g, char* lds) {
    __builtin_amdgcn_global_load_lds((const __attribute__((address_space(1))) unsigned int*)g,
                                     (__attribute__((address_space(3))) unsigned int*)lds, 16, 0,
                                     0);
}

// ---------------- small prep kernels ----------------
__global__ void k_convert_w(const float* __restrict__ wqkv, const float* __restrict__ wout,
                            bf16_t* __restrict__ wqkv_b, bf16_t* __restrict__ wout_b) {
    int idx = blockIdx.x * 256 + threadIdx.x;
    if (idx < 384 * 256) wqkv_b[idx] = (bf16_t)wqkv[idx];
    int j = idx - 384 * 256;
    if (j >= 0 && j < 256 * 128) wout_b[j] = (bf16_t)wout[j];
}

__global__ void k_xmean(const float* __restrict__ x, float* __restrict__ xmean) {
    int c = blockIdx.x, b = blockIdx.y;
    const float4* xv = (const float4*)(x + ((size_t)(b * CH + c)) * NPOS);
    float s = 0.f;
#pragma unroll
    for (int r = 0; r < 4; r++) {
        float4 v = xv[r * 256 + threadIdx.x];
        s += v.x + v.y + v.z + v.w;
    }
    __shared__ float red[256];
    red[threadIdx.x] = s;
    __syncthreads();
    for (int st = 128; st > 0; st >>= 1) {
        if (threadIdx.x < st) red[threadIdx.x] += red[threadIdx.x + st];
        __syncthreads();
    }
    if (threadIdx.x == 0) xmean[b * CH + c] = red[0] * (1.0f / NPOS);
}

// qkmean[b][o] = sum_c w_qkv[o][c] * xmean[b][c]   (bias cancels in centering)
__global__ void k_qkmean(const float* __restrict__ wqkv, const float* __restrict__ xmean,
                         float* __restrict__ qkm) {
    int o = blockIdx.x, b = blockIdx.y, lane = threadIdx.x;
    float4 w = ((const float4*)(wqkv + (size_t)o * CH))[lane];
    float4 xm = ((const float4*)(xmean + b * CH))[lane];
    float s = w.x * xm.x + w.y * xm.y + w.z * xm.z + w.w * xm.w;
#pragma unroll
    for (int m = 1; m < 64; m <<= 1) s += __shfl_xor(s, m, 64);
    if (lane == 0) qkm[b * CH + o] = s;
}

// x [b][256][4096] f32 -> x_t [b][4096][256] bf16
__global__ void k_transpose(const float* __restrict__ x, bf16_t* __restrict__ xt) {
    __shared__ float t[32][33];
    int p0 = blockIdx.x * 32, c0 = blockIdx.y * 32, b = blockIdx.z;
    int i = threadIdx.x >> 5, j = threadIdx.x & 31;
#pragma unroll
    for (int q = 0; q < 4; q++) {
        int c = c0 + q * 8 + i;
        t[q * 8 + i][j] = x[((size_t)(b * CH + c)) * NPOS + p0 + j];
    }
    __syncthreads();
#pragma unroll
    for (int q = 0; q < 4; q++) {
        int p = p0 + q * 8 + i;
        xt[((size_t)(b * NPOS + p)) * CH + c0 + j] = (bf16_t)t[j][q * 8 + i];
    }
}

// ---------------- QKV projection ----------------
__global__ __launch_bounds__(256, 2) void k_qkv(const bf16_t* __restrict__ xt,
                                                const bf16_t* __restrict__ wqkv_b,
                                                const float* __restrict__ qkm,
                                                const float* __restrict__ b_qkv,
                                                bf16_t* __restrict__ qt, bf16_t* __restrict__ kt,
                                                bf16_t* __restrict__ v) {
    int bid = blockIdx.x;
    int b = bid & 7;
    int r0 = bid >> 3;  // 0..95
    int sec = r0 % 3;
    int pt = r0 / 3;
    int p0 = pt * 128;
    int wid = threadIdx.x >> 6, lane = threadIdx.x & 63;
    int g = lane >> 4, li = lane & 15;
    int wr = wid >> 1, wc = wid & 1;
    f32x4 acc[4][4] = {};
    if (sec < 2) {
        int ob = sec * 128;
#pragma unroll 1
        for (int kk = 0; kk < 8; kk++) {
            bf16x8 af[4], bfg[4];
#pragma unroll
            for (int fa = 0; fa < 4; fa++) {
                int p = p0 + wr * 64 + fa * 16 + li;
                af[fa] = *(const bf16x8*)(xt + ((size_t)(b * NPOS + p)) * CH + kk * 32 + g * 8);
            }
#pragma unroll
            for (int fb = 0; fb < 4; fb++) {
                int o = ob + wc * 64 + fb * 16 + li;
                bfg[fb] = *(const bf16x8*)(wqkv_b + (size_t)o * CH + kk * 32 + g * 8);
            }
#pragma unroll
            for (int fa = 0; fa < 4; fa++)
#pragma unroll
                for (int fb = 0; fb < 4; fb++) acc[fa][fb] = MFMA16(af[fa], bfg[fb], acc[fa][fb]);
        }
        bf16_t* dst = (sec == 0) ? qt : kt;
#pragma unroll
        for (int fb = 0; fb < 4; fb++) {
            int ol = wc * 64 + fb * 16 + li;
            float mean = qkm[b * CH + sec * 128 + ol];
#pragma unroll
            for (int fa = 0; fa < 4; fa++)
#pragma unroll
                for (int r = 0; r < 4; r++) {
                    int p = p0 + wr * 64 + fa * 16 + g * 4 + r;
                    dst[((size_t)(b * NPOS + p)) * IC + ol] = (bf16_t)(acc[fa][fb][r] - mean);
                }
        }
    } else {
#pragma unroll 1
        for (int kk = 0; kk < 8; kk++) {
            bf16x8 af[4], bfg[4];
#pragma unroll
            for (int fa = 0; fa < 4; fa++) {
                int o = 256 + wr * 64 + fa * 16 + li;
                af[fa] = *(const bf16x8*)(wqkv_b + (size_t)o * CH + kk * 32 + g * 8);
            }
#pragma unroll
            for (int fb = 0; fb < 4; fb++) {
                int p = p0 + wc * 64 + fb * 16 + li;
                bfg[fb] = *(const bf16x8*)(xt + ((size_t)(b * NPOS + p)) * CH + kk * 32 + g * 8);
            }
#pragma unroll
            for (int fa = 0; fa < 4; fa++)
#pragma unroll
                for (int fb = 0; fb < 4; fb++) acc[fa][fb] = MFMA16(af[fa], bfg[fb], acc[fa][fb]);
        }
#pragma unroll
        for (int fa = 0; fa < 4; fa++)
#pragma unroll
            for (int r = 0; r < 4; r++) {
                int oe = wr * 64 + fa * 16 + g * 4 + r;
                float bias = b_qkv[256 + oe];
#pragma unroll
                for (int fb = 0; fb < 4; fb++) {
                    int p = p0 + wc * 64 + fb * 16 + li;
                    v[((size_t)(b * IC + oe)) * NPOS + p] = (bf16_t)(acc[fa][fb][r] + bias);
                }
            }
    }
}

// ---------------- flash attention (j-split, partial outputs) ----------------
// rows i <- k_t, cols j <- q_t, values v[c][j].
// grid 512: b = bid&7, r = bid>>3: jh = r&1 (j half), it = r>>1 (i-tile of 128).
// 4 waves x 32 i-rows. Swapped QK^T (MFMA(bq,a)) so P packs to b64 LDS writes.
// Outputs: pacc bf16 [b][jh][i][c] (unnormalized), pl f32 [b][jh][i].
constexpr int TJ = 64;

__global__ __launch_bounds__(256, 2) void k_attn(const bf16_t* __restrict__ qt,
                                                 const bf16_t* __restrict__ kt,
                                                 const bf16_t* __restrict__ v,
                                                 bf16_t* __restrict__ pacc,
                                                 float* __restrict__ pl) {
    // LDS: 2 x (q 16KB + v 16KB) dbuf + per-wave P [32][64] bf16 swizzled = 80KB
    __shared__ __attribute__((aligned(128))) char smem[2 * 32768 + 4 * 32 * 128];
    const int bid = blockIdx.x;
    const int b = bid & 7;
    const int r0 = bid >> 3;
    const int jh = r0 & 1;
    const int it = r0 >> 1;  // 0..31
    const int jbase = jh * 2048;
    const int wid = threadIdx.x >> 6, lane = threadIdx.x & 63;
    const int g = lane >> 4, li = lane & 15;
    const int iw0 = it * 128 + wid * 32;
    const bf16_t* ktb = kt + (size_t)b * NPOS * IC;
    const bf16_t* qtb = qt + (size_t)b * NPOS * IC;
    const bf16_t* vb = v + (size_t)b * IC * NPOS;
    char* pw = smem + 65536 + wid * 4096;  // this wave's P buffer [32 rows][128 B]

    // staging lane offsets (pre-swizzled global source: chunk ^= row&7)
    int qoff_[4], voff_[4];
#pragma unroll
    for (int u = 0; u < 4; u++) {
        int t = wid * 4 + u;
        int qrow = 4 * t + (lane >> 4);  // q-tile [64][256B]: 16 chunks/row
        qoff_[u] = qrow * 256 + (((lane & 15) ^ (qrow & 7)) << 4);
        int vrow = 8 * t + (lane >> 3);  // v-tile [128][128B]: 8 chunks/row
        voff_[u] = vrow * 8192 + (((lane & 7) ^ (vrow & 7)) << 4);
    }

    auto stage = [&](int dstpar, int sj) {
        const char* qs = (const char*)qtb + (size_t)sj * 256;
        const char* vs = (const char*)vb + (size_t)sj * 2;
        char* qd = smem + dstpar * 32768;
        char* vd = qd + 16384;
#pragma unroll
        for (int u = 0; u < 4; u++) {
            gload_lds16(qs + qoff_[u], qd + (wid * 4 + u) * 1024);
            gload_lds16(vs + voff_[u], vd + (wid * 4 + u) * 1024);
        }
    };

    stage(0, jbase);  // prologue (8 loads in flight)

    // B-operand fragments: this wave's 32 i-rows (kept in registers)
    bf16x8 a[2][4];
#pragma unroll
    for (int fi = 0; fi < 2; fi++)
#pragma unroll
        for (int kk = 0; kk < 4; kk++)
            a[fi][kk] = *(const bf16x8*)(ktb + (size_t)(iw0 + fi * 16 + li) * IC + kk * 32 + g * 8);

    f32x4 acc[2][8] = {};
    float lsum[2] = {0.f, 0.f};

    auto body = [&](int par, int nextj) {
        stage(par ^ 1, nextj);                            // prefetch next tile (8 loads)
        asm volatile("s_waitcnt vmcnt(8)" ::: "memory");  // current tile's loads done
        __builtin_amdgcn_s_barrier();
        asm volatile("" ::: "memory");
        const char* qb = smem + par * 32768;
        const char* vbuf = qb + 16384;
        // QK^T, swapped: s[fi][jf] holds S[j=jf*16+g*4+r][i=fi*16+li]
        f32x4 s[2][4] = {};
#pragma unroll
        for (int jf = 0; jf < 4; jf++) {
            bf16x8 bq[4];
#pragma unroll
            for (int kk = 0; kk < 4; kk++)
                bq[kk] = *(const bf16x8*)(qb + (jf * 16 + li) * 256 +
                                          (((kk * 4 + g) ^ (li & 7)) << 4));
#pragma unroll
            for (int fi = 0; fi < 2; fi++)
#pragma unroll
                for (int kk = 0; kk < 4; kk++) s[fi][jf] = MFMA16(bq[kk], a[fi][kk], s[fi][jf]);
        }
        // exp2, lane-local row-sum, packed b64 store into swizzled P[i][j]
#pragma unroll
        for (int fi = 0; fi < 2; fi++) {
            int row = fi * 16 + li;
#pragma unroll
            for (int jf = 0; jf < 4; jf++) {
                float p0 = exp2f(s[fi][jf][0] * SM_C);
                float p1 = exp2f(s[fi][jf][1] * SM_C);
                float p2 = exp2f(s[fi][jf][2] * SM_C);
                float p3 = exp2f(s[fi][jf][3] * SM_C);
                lsum[fi] += (p0 + p1) + (p2 + p3);
                bf16x4 pk = {(bf16_t)p0, (bf16_t)p1, (bf16_t)p2, (bf16_t)p3};
                *(bf16x4*)(pw + row * 128 + ((((jf * 2 + (g >> 1)) ^ (row & 7))) << 4) +
                           ((g & 1) << 3)) = pk;
            }
        }
        // PV: A = P rows (this wave), B = v cols
#pragma unroll
        for (int jj = 0; jj < 2; jj++) {
            bf16x8 pf[2];
#pragma unroll
            for (int fi = 0; fi < 2; fi++) {
                int row = fi * 16 + li;
                pf[fi] = *(const bf16x8*)(pw + row * 128 + (((jj * 4 + g) ^ (row & 7)) << 4));
            }
#pragma unroll
            for (int cf = 0; cf < 8; cf++) {
                bf16x8 vf = *(const bf16x8*)(vbuf + (cf * 16 + li) * 128 +
                                             (((jj * 4 + g) ^ (li & 7)) << 4));
#pragma unroll
                for (int fi = 0; fi < 2; fi++) acc[fi][cf] = MFMA16(pf[fi], vf, acc[fi][cf]);
            }
        }
        asm volatile("" ::: "memory");
        __builtin_amdgcn_s_barrier();  // all reads of cur buffer done before restage
    };

#pragma unroll 1
    for (int jo = 0; jo < 2048; jo += 2 * TJ) {
        body(0, jbase + ((jo + TJ) & 2047));
        body(1, jbase + ((jo + 2 * TJ) & 2047));
    }

    // reduce lsum across the 4 g-groups (same i lives in lanes li, li+16, li+32, li+48)
#pragma unroll
    for (int fi = 0; fi < 2; fi++) {
        lsum[fi] += __shfl_xor(lsum[fi], 16, 64);
        lsum[fi] += __shfl_xor(lsum[fi], 32, 64);
    }
    if (g == 0) {
#pragma unroll
        for (int fi = 0; fi < 2; fi++)
            pl[((size_t)(b * 2 + jh)) * NPOS + iw0 + fi * 16 + li] = lsum[fi];
    }
    bf16_t* po = pacc + ((size_t)(b * 2 + jh)) * NPOS * IC;
#pragma unroll
    for (int fi = 0; fi < 2; fi++)
#pragma unroll
        for (int r = 0; r < 4; r++) {
            int i = iw0 + fi * 16 + g * 4 + r;
#pragma unroll
            for (int cf = 0; cf < 8; cf++)
                po[(size_t)i * IC + cf * 16 + li] = (bf16_t)acc[fi][cf][r];
        }
}

// ---------------- merge partials: yt = (A0+A1)/(l0+l1) ----------------
__global__ void k_merge(const bf16_t* __restrict__ pacc, const float* __restrict__ pl,
                        bf16_t* __restrict__ yt) {
    int idx = blockIdx.x * 256 + threadIdx.x;  // over [8 b][4096 i][16 c-oct]
    int co = idx & 15;
    int i = (idx >> 4) & 4095;
    int b = idx >> 16;
    const bf16x8* p0 = (const bf16x8*)pacc + ((size_t)(b * 2 + 0) * NPOS + i) * 16 + co;
    const bf16x8* p1 = (const bf16x8*)pacc + ((size_t)(b * 2 + 1) * NPOS + i) * 16 + co;
    float l = pl[(size_t)(b * 2 + 0) * NPOS + i] + pl[(size_t)(b * 2 + 1) * NPOS + i];
    float inv = 1.0f / l;
    bf16x8 a0 = *p0, a1 = *p1, o;
#pragma unroll
    for (int j = 0; j < 8; j++) o[j] = (bf16_t)(((float)a0[j] + (float)a1[j]) * inv);
    *((bf16x8*)yt + ((size_t)b * NPOS + i) * 16 + co) = o;
}

// ---------------- output projection + residual ----------------
__global__ __launch_bounds__(256, 2) void k_out(const bf16_t* __restrict__ yt,
                                                const bf16_t* __restrict__ wout_b,
                                                const float* __restrict__ x,
                                                const float* __restrict__ b_out,
                                                float* __restrict__ out) {
    int bid = blockIdx.x;
    int b = bid & 7;
    int r0 = bid >> 3;
    int oct = r0 & 1, pt = r0 >> 1;
    int p0 = pt * 128, oc0 = oct * 128;
    int wid = threadIdx.x >> 6, lane = threadIdx.x & 63;
    int g = lane >> 4, li = lane & 15;
    int wr = wid >> 1, wc = wid & 1;
    f32x4 acc[4][4] = {};
#pragma unroll
    for (int kk = 0; kk < 4; kk++) {
        bf16x8 af[4], bfg[4];
#pragma unroll
        for (int fa = 0; fa < 4; fa++) {
            int oc = oc0 + wr * 64 + fa * 16 + li;
            af[fa] = *(const bf16x8*)(wout_b + (size_t)oc * IC + kk * 32 + g * 8);
        }
#pragma unroll
        for (int fb = 0; fb < 4; fb++) {
            int p = p0 + wc * 64 + fb * 16 + li;
            bfg[fb] = *(const bf16x8*)(yt + ((size_t)(b * NPOS + p)) * IC + kk * 32 + g * 8);
        }
#pragma unroll
        for (int fa = 0; fa < 4; fa++)
#pragma unroll
            for (int fb = 0; fb < 4; fb++) acc[fa][fb] = MFMA16(af[fa], bfg[fb], acc[fa][fb]);
    }
#pragma unroll
    for (int fa = 0; fa < 4; fa++)
#pragma unroll
        for (int r = 0; r < 4; r++) {
            int oc = oc0 + wr * 64 + fa * 16 + g * 4 + r;
            float bias = b_out[oc];
#pragma unroll
            for (int fb = 0; fb < 4; fb++) {
                int p = p0 + wc * 64 + fb * 16 + li;
                size_t idx = ((size_t)(b * CH + oc)) * NPOS + p;
                out[idx] = acc[fa][fb][r] + x[idx] + bias;
            }
        }
}

extern "C" void kernel_launch(void* const* d_in, const int* in_sizes, int n_in, void* d_out,
                              int out_size, void* d_ws, size_t ws_size, hipStream_t stream) {
    const float* x = (const float*)d_in[0];
    const float* w_qkv = (const float*)d_in[1];
    const float* b_qkv = (const float*)d_in[2];
    const float* w_out = (const float*)d_in[3];
    const float* b_out = (const float*)d_in[4];
    float* out = (float*)d_out;
    char* ws = (char*)d_ws;

    bf16_t* xt = (bf16_t*)(ws + OFF_XT);
    bf16_t* pacc = (bf16_t*)(ws + OFF_XT);  // reuses x_t (dead after k_qkv), exact fit
    bf16_t* qt = (bf16_t*)(ws + OFF_QT);
    bf16_t* kt = (bf16_t*)(ws + OFF_KT);
    bf16_t* yt = (bf16_t*)(ws + OFF_KT);  // reuses k_t (dead after k_attn)
    bf16_t* v = (bf16_t*)(ws + OFF_V);
    bf16_t* wqkv_b = (bf16_t*)(ws + OFF_WQKV);
    bf16_t* wout_b = (bf16_t*)(ws + OFF_WOUT);
    float* xmean = (float*)(ws + OFF_XMEAN);
    float* qkm = (float*)(ws + OFF_QKM);
    float* pl = (float*)(ws + OFF_PL);

    k_convert_w<<<512, 256, 0, stream>>>(w_qkv, w_out, wqkv_b, wout_b);
    k_xmean<<<dim3(256, 8), 256, 0, stream>>>(x, xmean);
    k_qkmean<<<dim3(256, 8), 64, 0, stream>>>(w_qkv, xmean, qkm);
    k_transpose<<<dim3(128, 8, 8), 256, 0, stream>>>(x, xt);
    k_qkv<<<768, 256, 0, stream>>>(xt, wqkv_b, qkm, b_qkv, qt, kt, v);
    k_attn<<<512, 256, 0, stream>>>(qt, kt, v, pacc, pl);
    k_merge<<<2048, 256, 0, stream>>>(pacc, pl, yt);
    k_out<<<512, 256, 0, stream>>>(yt, wout_b, x, b_out, out);
}

// Round 4
// 149.182 us; speedup vs baseline: 3.2325x; 1.0947x over previous
//
#include <hip/hip_runtime.h>
#include <hip/hip_bf16.h>

typedef __bf16 bf16_t;
typedef __bf16 bf16x8 __attribute__((ext_vector_type(8)));
typedef float f32x4 __attribute__((ext_vector_type(4)));
typedef float f32x16 __attribute__((ext_vector_type(16)));

#define MFMA16(a, b, c) __builtin_amdgcn_mfma_f32_16x16x32_bf16((a), (b), (c), 0, 0, 0)
#define MFMA32(a, b, c) __builtin_amdgcn_mfma_f32_32x32x16_bf16((a), (b), (c), 0, 0, 0)

constexpr int BATCH = 8, CH = 256, IC = 128, NPOS = 4096;
// softmax scale: 1/(sqrt(128)*0.05) * log2(e)  — folded into kt at k_qkv epilogue
constexpr float SM_C = 2.5503488f;

// ---- workspace layout (bytes) ----
constexpr size_t OFF_XT    = 0;         // bf16 [8][4096][256] x_t; later pacc bf16 [8][2][4096][128]
constexpr size_t OFF_QT    = 16777216;  // bf16 [8][4096][128] (centered)
constexpr size_t OFF_KT    = 25165824;  // bf16 [8][4096][128] (centered, *SM_C); later yt
constexpr size_t OFF_V     = 33554432;  // bf16 [8][128][4096]
constexpr size_t OFF_WQKV  = 41943040;  // bf16 [384][256]
constexpr size_t OFF_WOUT  = 42139648;  // bf16 [256][128]
constexpr size_t OFF_XMEAN = 42205184;  // f32 [8][256]
constexpr size_t OFF_QKM   = 42213376;  // f32 [8][256]
constexpr size_t OFF_PL    = 42221568;  // f32 [8][2][4096]

__device__ __forceinline__ void gload_lds16(const char* g, char* lds) {
    __builtin_amdgcn_global_load_lds((const __attribute__((address_space(1))) unsigned int*)g,
                                     (__attribute__((address_space(3))) unsigned int*)lds, 16, 0,
                                     0);
}
__device__ __forceinline__ float fexp2(float x) {
    float r;
    asm("v_exp_f32 %0, %1" : "=v"(r) : "v"(x));
    return r;
}
__device__ __forceinline__ int cvtpk(float lo, float hi) {
    int r;
    asm("v_cvt_pk_bf16_f32 %0, %1, %2" : "=v"(r) : "v"(lo), "v"(hi));
    return r;
}

// ---------------- small prep kernels ----------------
__global__ void k_convert_w(const float* __restrict__ wqkv, const float* __restrict__ wout,
                            bf16_t* __restrict__ wqkv_b, bf16_t* __restrict__ wout_b) {
    int idx = blockIdx.x * 256 + threadIdx.x;
    if (idx < 384 * 256) wqkv_b[idx] = (bf16_t)wqkv[idx];
    int j = idx - 384 * 256;
    if (j >= 0 && j < 256 * 128) wout_b[j] = (bf16_t)wout[j];
}

__global__ void k_xmean(const float* __restrict__ x, float* __restrict__ xmean) {
    int c = blockIdx.x, b = blockIdx.y;
    const float4* xv = (const float4*)(x + ((size_t)(b * CH + c)) * NPOS);
    float s = 0.f;
#pragma unroll
    for (int r = 0; r < 4; r++) {
        float4 v = xv[r * 256 + threadIdx.x];
        s += v.x + v.y + v.z + v.w;
    }
    __shared__ float red[256];
    red[threadIdx.x] = s;
    __syncthreads();
    for (int st = 128; st > 0; st >>= 1) {
        if (threadIdx.x < st) red[threadIdx.x] += red[threadIdx.x + st];
        __syncthreads();
    }
    if (threadIdx.x == 0) xmean[b * CH + c] = red[0] * (1.0f / NPOS);
}

// qkmean[b][o] = sum_c w_qkv[o][c] * xmean[b][c]   (bias cancels in centering)
__global__ void k_qkmean(const float* __restrict__ wqkv, const float* __restrict__ xmean,
                         float* __restrict__ qkm) {
    int o = blockIdx.x, b = blockIdx.y, lane = threadIdx.x;
    float4 w = ((const float4*)(wqkv + (size_t)o * CH))[lane];
    float4 xm = ((const float4*)(xmean + b * CH))[lane];
    float s = w.x * xm.x + w.y * xm.y + w.z * xm.z + w.w * xm.w;
#pragma unroll
    for (int m = 1; m < 64; m <<= 1) s += __shfl_xor(s, m, 64);
    if (lane == 0) qkm[b * CH + o] = s;
}

// x [b][256][4096] f32 -> x_t [b][4096][256] bf16
__global__ void k_transpose(const float* __restrict__ x, bf16_t* __restrict__ xt) {
    __shared__ float t[32][33];
    int p0 = blockIdx.x * 32, c0 = blockIdx.y * 32, b = blockIdx.z;
    int i = threadIdx.x >> 5, j = threadIdx.x & 31;
#pragma unroll
    for (int q = 0; q < 4; q++) {
        int c = c0 + q * 8 + i;
        t[q * 8 + i][j] = x[((size_t)(b * CH + c)) * NPOS + p0 + j];
    }
    __syncthreads();
#pragma unroll
    for (int q = 0; q < 4; q++) {
        int p = p0 + q * 8 + i;
        xt[((size_t)(b * NPOS + p)) * CH + c0 + j] = (bf16_t)t[j][q * 8 + i];
    }
}

// ---------------- QKV projection ----------------
__global__ __launch_bounds__(256, 2) void k_qkv(const bf16_t* __restrict__ xt,
                                                const bf16_t* __restrict__ wqkv_b,
                                                const float* __restrict__ qkm,
                                                const float* __restrict__ b_qkv,
                                                bf16_t* __restrict__ qt, bf16_t* __restrict__ kt,
                                                bf16_t* __restrict__ v) {
    int bid = blockIdx.x;
    int b = bid & 7;
    int r0 = bid >> 3;  // 0..95
    int sec = r0 % 3;
    int pt = r0 / 3;
    int p0 = pt * 128;
    int wid = threadIdx.x >> 6, lane = threadIdx.x & 63;
    int g = lane >> 4, li = lane & 15;
    int wr = wid >> 1, wc = wid & 1;
    f32x4 acc[4][4] = {};
    if (sec < 2) {
        int ob = sec * 128;
#pragma unroll 1
        for (int kk = 0; kk < 8; kk++) {
            bf16x8 af[4], bfg[4];
#pragma unroll
            for (int fa = 0; fa < 4; fa++) {
                int p = p0 + wr * 64 + fa * 16 + li;
                af[fa] = *(const bf16x8*)(xt + ((size_t)(b * NPOS + p)) * CH + kk * 32 + g * 8);
            }
#pragma unroll
            for (int fb = 0; fb < 4; fb++) {
                int o = ob + wc * 64 + fb * 16 + li;
                bfg[fb] = *(const bf16x8*)(wqkv_b + (size_t)o * CH + kk * 32 + g * 8);
            }
#pragma unroll
            for (int fa = 0; fa < 4; fa++)
#pragma unroll
                for (int fb = 0; fb < 4; fb++) acc[fa][fb] = MFMA16(af[fa], bfg[fb], acc[fa][fb]);
        }
        bf16_t* dst = (sec == 0) ? qt : kt;
        float scale = (sec == 1) ? SM_C : 1.0f;  // fold softmax scale into k
#pragma unroll
        for (int fb = 0; fb < 4; fb++) {
            int ol = wc * 64 + fb * 16 + li;
            float mean = qkm[b * CH + sec * 128 + ol];
#pragma unroll
            for (int fa = 0; fa < 4; fa++)
#pragma unroll
                for (int r = 0; r < 4; r++) {
                    int p = p0 + wr * 64 + fa * 16 + g * 4 + r;
                    dst[((size_t)(b * NPOS + p)) * IC + ol] =
                        (bf16_t)((acc[fa][fb][r] - mean) * scale);
                }
        }
    } else {
#pragma unroll 1
        for (int kk = 0; kk < 8; kk++) {
            bf16x8 af[4], bfg[4];
#pragma unroll
            for (int fa = 0; fa < 4; fa++) {
                int o = 256 + wr * 64 + fa * 16 + li;
                af[fa] = *(const bf16x8*)(wqkv_b + (size_t)o * CH + kk * 32 + g * 8);
            }
#pragma unroll
            for (int fb = 0; fb < 4; fb++) {
                int p = p0 + wc * 64 + fb * 16 + li;
                bfg[fb] = *(const bf16x8*)(xt + ((size_t)(b * NPOS + p)) * CH + kk * 32 + g * 8);
            }
#pragma unroll
            for (int fa = 0; fa < 4; fa++)
#pragma unroll
                for (int fb = 0; fb < 4; fb++) acc[fa][fb] = MFMA16(af[fa], bfg[fb], acc[fa][fb]);
        }
#pragma unroll
        for (int fa = 0; fa < 4; fa++)
#pragma unroll
            for (int r = 0; r < 4; r++) {
                int oe = wr * 64 + fa * 16 + g * 4 + r;
                float bias = b_qkv[256 + oe];
#pragma unroll
                for (int fb = 0; fb < 4; fb++) {
                    int p = p0 + wc * 64 + fb * 16 + li;
                    v[((size_t)(b * IC + oe)) * NPOS + p] = (bf16_t)(acc[fa][fb][r] + bias);
                }
            }
    }
}

// ---------------- flash attention (32x32 MFMA, in-register P) ----------------
// rows j <- q_t (MFMA M dim), cols i <- k_t (MFMA N dim), values v[c][j].
// grid 512: b = bid&7, r = bid>>3: jh = r&1 (j half), it = r>>1 (i-tile of 128).
// 4 waves x 32 i-cols each. D(QK^T)[j][i] -> cvt_pk + permlane32_swap -> B-frag of PV.
constexpr int TJ = 64;

__global__ __launch_bounds__(256, 2) void k_attn(const bf16_t* __restrict__ qt,
                                                 const bf16_t* __restrict__ kt,
                                                 const bf16_t* __restrict__ v,
                                                 bf16_t* __restrict__ pacc,
                                                 float* __restrict__ pl) {
    // LDS: 2 x (q 16KB + v 16KB) double buffer = 64KB. No P buffer.
    __shared__ __attribute__((aligned(128))) char smem[2 * 32768];
    const int bid = blockIdx.x;
    const int b = bid & 7;
    const int r0 = bid >> 3;
    const int jh = r0 & 1;
    const int it = r0 >> 1;  // 0..31
    const int jbase = jh * 2048;
    const int wid = threadIdx.x >> 6, lane = threadIdx.x & 63;
    const int col = lane & 31, h = lane >> 5;  // i-col within wave tile, lane half
    const int iw0 = it * 128 + wid * 32;
    const bf16_t* ktb = kt + (size_t)b * NPOS * IC;
    const bf16_t* qtb = qt + (size_t)b * NPOS * IC;
    const bf16_t* vb = v + (size_t)b * IC * NPOS;

    // staging lane offsets (pre-swizzled global source: chunk ^= row&7)
    int qoff_[4], voff_[4];
#pragma unroll
    for (int u = 0; u < 4; u++) {
        int t = wid * 4 + u;
        int qrow = 4 * t + (lane >> 4);  // q-tile [64][256B]: 16 chunks/row
        qoff_[u] = qrow * 256 + (((lane & 15) ^ (qrow & 7)) << 4);
        int vrow = 8 * t + (lane >> 3);  // v-tile [128][128B]: 8 chunks/row
        voff_[u] = vrow * 8192 + (((lane & 7) ^ (vrow & 7)) << 4);
    }

    auto stage = [&](int dstpar, int sj) {
        const char* qs = (const char*)qtb + (size_t)sj * 256;
        const char* vs = (const char*)vb + (size_t)sj * 2;
        char* qd = smem + dstpar * 32768;
        char* vd = qd + 16384;
#pragma unroll
        for (int u = 0; u < 4; u++) {
            gload_lds16(qs + qoff_[u], qd + (wid * 4 + u) * 1024);
            gload_lds16(vs + voff_[u], vd + (wid * 4 + u) * 1024);
        }
    };

    stage(0, jbase);  // prologue (8 loads in flight)

    // B-operand (k rows): this wave's 32 i-cols, kept in registers. k = c dim.
    bf16x8 bk[8];
#pragma unroll
    for (int ks = 0; ks < 8; ks++)
        bk[ks] = *(const bf16x8*)(ktb + (size_t)(iw0 + col) * IC + ks * 16 + h * 8);

    f32x16 acc[4] = {};  // D(PV)[c][i]: 4 c-subtiles of 32
    float ls[4] = {0.f, 0.f, 0.f, 0.f};

    auto body = [&](int par, int nextj) {
        stage(par ^ 1, nextj);                            // prefetch next tile (8 loads)
        asm volatile("s_waitcnt vmcnt(8)" ::: "memory");  // current tile's loads done
        __builtin_amdgcn_s_barrier();
        asm volatile("" ::: "memory");
        const char* qb = smem + par * 32768;
        const char* vbuf = qb + 16384;
#pragma unroll
        for (int jsub = 0; jsub < 2; jsub++) {
            // QK^T: D[j][i], A = q rows from LDS, B = bk
            f32x16 s = {};
#pragma unroll
            for (int ks = 0; ks < 8; ks++) {
                bf16x8 aq = *(const bf16x8*)(qb + (jsub * 32 + col) * 256 +
                                             (((ks * 2 + h) ^ (col & 7)) << 4));
                s = MFMA32(aq, bk[ks], s);
            }
            // exp2 (scale pre-folded into kt), lane-local row-sum
            float e[16];
#pragma unroll
            for (int r = 0; r < 16; r++) e[r] = fexp2(s[r]);
#pragma unroll
            for (int r = 0; r < 16; r++) ls[r & 3] += e[r];
            // pack to bf16 pairs, then lane<->lane+32 swap => PV B-fragments
            int w[8];
#pragma unroll
            for (int q = 0; q < 8; q++) w[q] = cvtpk(e[2 * q], e[2 * q + 1]);
            asm("v_permlane32_swap_b32 %0, %1" : "+v"(w[0]), "+v"(w[2]));
            asm("v_permlane32_swap_b32 %0, %1" : "+v"(w[1]), "+v"(w[3]));
            asm("v_permlane32_swap_b32 %0, %1" : "+v"(w[4]), "+v"(w[6]));
            asm("v_permlane32_swap_b32 %0, %1" : "+v"(w[5]), "+v"(w[7]));
            union {
                int u[4];
                bf16x8 v;
            } pb0, pb1;
            pb0.u[0] = w[0]; pb0.u[1] = w[1]; pb0.u[2] = w[2]; pb0.u[3] = w[3];
            pb1.u[0] = w[4]; pb1.u[1] = w[5]; pb1.u[2] = w[6]; pb1.u[3] = w[7];
            // PV: D[c][i] += v-frag * P-frag, over this jsub's 32 j (2 k-steps)
#pragma unroll
            for (int kl = 0; kl < 2; kl++) {
                int kg = jsub * 2 + kl;  // 16-j group within 64-j tile
                bf16x8 pbf = kl == 0 ? pb0.v : pb1.v;
#pragma unroll
                for (int cs = 0; cs < 4; cs++) {
                    bf16x8 av = *(const bf16x8*)(vbuf + (cs * 32 + col) * 128 +
                                                 (((kg * 2 + h) ^ (col & 7)) << 4));
                    acc[cs] = MFMA32(av, pbf, acc[cs]);
                }
            }
        }
        asm volatile("" ::: "memory");
        __builtin_amdgcn_s_barrier();  // all reads of cur buffer done before restage
    };

#pragma unroll 1
    for (int jo = 0; jo < 2048; jo += 2 * TJ) {
        body(0, jbase + ((jo + TJ) & 2047));
        body(1, jbase + ((jo + 2 * TJ) & 2047));
    }

    // denominator: lane-local sums + lane<->lane+32 combine
    float lsum = (ls[0] + ls[1]) + (ls[2] + ls[3]);
    lsum += __shfl_xor(lsum, 32, 64);
    const int i = iw0 + col;
    if (h == 0) pl[((size_t)(b * 2 + jh)) * NPOS + i] = lsum;

    // store partial accumulator: D[c][i] layout: c = cs*32 + (r&3)+8*(r>>2)+4h
    bf16_t* po = pacc + ((size_t)(b * 2 + jh)) * NPOS * IC;
#pragma unroll
    for (int cs = 0; cs < 4; cs++)
#pragma unroll
        for (int q = 0; q < 8; q++) {
            int u = cvtpk(acc[cs][2 * q], acc[cs][2 * q + 1]);
            int c0 = cs * 32 + ((q & 1) << 1) + ((q >> 1) << 3) + 4 * h;
            *(int*)((char*)po + ((size_t)i * IC + c0) * 2) = u;
        }
}

// ---------------- merge partials: yt = (A0+A1)/(l0+l1) ----------------
__global__ void k_merge(const bf16_t* __restrict__ pacc, const float* __restrict__ pl,
                        bf16_t* __restrict__ yt) {
    int idx = blockIdx.x * 256 + threadIdx.x;  // over [8 b][4096 i][16 c-oct]
    int co = idx & 15;
    int i = (idx >> 4) & 4095;
    int b = idx >> 16;
    const bf16x8* p0 = (const bf16x8*)pacc + ((size_t)(b * 2 + 0) * NPOS + i) * 16 + co;
    const bf16x8* p1 = (const bf16x8*)pacc + ((size_t)(b * 2 + 1) * NPOS + i) * 16 + co;
    float l = pl[(size_t)(b * 2 + 0) * NPOS + i] + pl[(size_t)(b * 2 + 1) * NPOS + i];
    float inv = 1.0f / l;
    bf16x8 a0 = *p0, a1 = *p1, o;
#pragma unroll
    for (int j = 0; j < 8; j++) o[j] = (bf16_t)(((float)a0[j] + (float)a1[j]) * inv);
    *((bf16x8*)yt + ((size_t)b * NPOS + i) * 16 + co) = o;
}

// ---------------- output projection + residual ----------------
__global__ __launch_bounds__(256, 2) void k_out(const bf16_t* __restrict__ yt,
                                                const bf16_t* __restrict__ wout_b,
                                                const float* __restrict__ x,
                                                const float* __restrict__ b_out,
                                                float* __restrict__ out) {
    int bid = blockIdx.x;
    int b = bid & 7;
    int r0 = bid >> 3;
    int oct = r0 & 1, pt = r0 >> 1;
    int p0 = pt * 128, oc0 = oct * 128;
    int wid = threadIdx.x >> 6, lane = threadIdx.x & 63;
    int g = lane >> 4, li = lane & 15;
    int wr = wid >> 1, wc = wid & 1;
    f32x4 acc[4][4] = {};
#pragma unroll
    for (int kk = 0; kk < 4; kk++) {
        bf16x8 af[4], bfg[4];
#pragma unroll
        for (int fa = 0; fa < 4; fa++) {
            int oc = oc0 + wr * 64 + fa * 16 + li;
            af[fa] = *(const bf16x8*)(wout_b + (size_t)oc * IC + kk * 32 + g * 8);
        }
#pragma unroll
        for (int fb = 0; fb < 4; fb++) {
            int p = p0 + wc * 64 + fb * 16 + li;
            bfg[fb] = *(const bf16x8*)(yt + ((size_t)(b * NPOS + p)) * IC + kk * 32 + g * 8);
        }
#pragma unroll
        for (int fa = 0; fa < 4; fa++)
#pragma unroll
            for (int fb = 0; fb < 4; fb++) acc[fa][fb] = MFMA16(af[fa], bfg[fb], acc[fa][fb]);
    }
#pragma unroll
    for (int fa = 0; fa < 4; fa++)
#pragma unroll
        for (int r = 0; r < 4; r++) {
            int oc = oc0 + wr * 64 + fa * 16 + g * 4 + r;
            float bias = b_out[oc];
#pragma unroll
            for (int fb = 0; fb < 4; fb++) {
                int p = p0 + wc * 64 + fb * 16 + li;
                size_t idx = ((size_t)(b * CH + oc)) * NPOS + p;
                out[idx] = acc[fa][fb][r] + x[idx] + bias;
            }
        }
}

extern "C" void kernel_launch(void* const* d_in, const int* in_sizes, int n_in, void* d_out,
                              int out_size, void* d_ws, size_t ws_size, hipStream_t stream) {
    const float* x = (const float*)d_in[0];
    const float* w_qkv = (const float*)d_in[1];
    const float* b_qkv = (const float*)d_in[2];
    const float* w_out = (const float*)d_in[3];
    const float* b_out = (const float*)d_in[4];
    float* out = (float*)d_out;
    char* ws = (char*)d_ws;

    bf16_t* xt = (bf16_t*)(ws + OFF_XT);
    bf16_t* pacc = (bf16_t*)(ws + OFF_XT);  // reuses x_t (dead after k_qkv), exact fit
    bf16_t* qt = (bf16_t*)(ws + OFF_QT);
    bf16_t* kt = (bf16_t*)(ws + OFF_KT);
    bf16_t* yt = (bf16_t*)(ws + OFF_KT);  // reuses k_t (dead after k_attn)
    bf16_t* v = (bf16_t*)(ws + OFF_V);
    bf16_t* wqkv_b = (bf16_t*)(ws + OFF_WQKV);
    bf16_t* wout_b = (bf16_t*)(ws + OFF_WOUT);
    float* xmean = (float*)(ws + OFF_XMEAN);
    float* qkm = (float*)(ws + OFF_QKM);
    float* pl = (float*)(ws + OFF_PL);

    k_convert_w<<<512, 256, 0, stream>>>(w_qkv, w_out, wqkv_b, wout_b);
    k_xmean<<<dim3(256, 8), 256, 0, stream>>>(x, xmean);
    k_qkmean<<<dim3(256, 8), 64, 0, stream>>>(w_qkv, xmean, qkm);
    k_transpose<<<dim3(128, 8, 8), 256, 0, stream>>>(x, xt);
    k_qkv<<<768, 256, 0, stream>>>(xt, wqkv_b, qkm, b_qkv, qt, kt, v);
    k_attn<<<512, 256, 0, stream>>>(qt, kt, v, pacc, pl);
    k_merge<<<2048, 256, 0, stream>>>(pacc, pl, yt);
    k_out<<<512, 256, 0, stream>>>(yt, wout_b, x, b_out, out);
}